// Round 10
// baseline (189.220 us; speedup 1.0000x reference)
//
#include <hip/hip_runtime.h>
#include <hip/hip_bf16.h>

// Problem constants
#define BB 2
#define TT 2048
#define CC 768
#define HH 8
#define DD 96
#define N3 2304   // 3*C
#define BH (BB*HH)

typedef __bf16 bf16x8 __attribute__((ext_vector_type(8)));
typedef float f32x4 __attribute__((ext_vector_type(4)));

__device__ __forceinline__ ushort f2bf(float f) {
    unsigned u = __builtin_bit_cast(unsigned, f);
    u += 0x7fffu + ((u >> 16) & 1u);   // round-to-nearest-even
    return (ushort)(u >> 16);
}
__device__ __forceinline__ float bf2f(ushort u) {
    return __builtin_bit_cast(float, (unsigned)u << 16);
}

// ---------------------------------------------------------------------------
// Cast fp32 -> bf16, flat
// ---------------------------------------------------------------------------
__global__ __launch_bounds__(256) void cast_bf16_kernel(
    const float* __restrict__ src, ushort* __restrict__ dst)
{
    const size_t i = ((size_t)blockIdx.x * 256 + threadIdx.x) * 8;
    float4 a = *(const float4*)&src[i];
    float4 b = *(const float4*)&src[i + 4];
    ushort tmp[8] = {f2bf(a.x), f2bf(a.y), f2bf(a.z), f2bf(a.w),
                     f2bf(b.x), f2bf(b.y), f2bf(b.z), f2bf(b.w)};
    *(uint4*)&dst[i] = *(const uint4*)tmp;
}

// ---------------------------------------------------------------------------
// Transpose-cast: src fp32 [R][C] -> dst bf16 [C][R].  64x64 LDS tiles.
// ---------------------------------------------------------------------------
__global__ __launch_bounds__(256) void tcast_bf16_kernel(
    const float* __restrict__ src, ushort* __restrict__ dst, int R, int C)
{
    __shared__ ushort t[64][66];
    const int tid = threadIdx.x;
    const int c0 = blockIdx.x * 64;
    const int r0 = blockIdx.y * 64;
    const int tx = tid & 63;
    const int ty = tid >> 6;
    #pragma unroll
    for (int i = 0; i < 16; ++i) {
        const int row = ty * 16 + i;
        t[tx][row] = f2bf(src[(size_t)(r0 + row) * C + c0 + tx]);
    }
    __syncthreads();
    #pragma unroll
    for (int i = 0; i < 16; ++i) {
        const int row = ty * 16 + i;
        dst[(size_t)(c0 + row) * R + r0 + tx] = t[row][tx];
    }
}

// ---------------------------------------------------------------------------
// Shared MFMA GEMM mainloop (R8 state, frozen): 64x128 tile, BK=32, K=768,
// triple-buffered counted-vmcnt pipeline.
// ---------------------------------------------------------------------------
__device__ __forceinline__ void mfma_gemm64_768(
    const ushort* __restrict__ A, const ushort* __restrict__ Bt,
    int m0, int n0, ushort* Al, ushort* Bl, f32x4 (&acc)[2][4])
{
    const int tid  = threadIdx.x;
    const int w    = tid >> 6;
    const int lane = tid & 63;
    const int quad = lane >> 4;
    const int col  = lane & 15;
    const int rm   = (w >> 1) * 32;     // wave row offset within 64
    const int cn   = (w & 1) * 64;      // wave col offset within 128

    const int row_s = tid >> 2, sub = tid & 3;   // 64 rows x 4 chunks
    const ushort* ga0 = A  + (size_t)(m0 + row_s) * 768 + sub * 8;
    const ushort* gb0 = Bt + (size_t)(n0 + row_s) * 768 + sub * 8;
    ushort* la0 = Al + tid * 8;         // linear within one A buffer (2048 el)
    ushort* lb0 = Bl + tid * 8;         // linear within one B buffer (4096 el)

#define GSTAGE(T, BUF) do {                                                   \
    __builtin_amdgcn_global_load_lds(                                         \
        (const __attribute__((address_space(1))) void*)(ga0 + (T)*32),        \
        (__attribute__((address_space(3))) void*)(la0 + (BUF)*2048), 16, 0, 0); \
    __builtin_amdgcn_global_load_lds(                                         \
        (const __attribute__((address_space(1))) void*)(gb0 + (T)*32),        \
        (__attribute__((address_space(3))) void*)(lb0 + (BUF)*4096), 16, 0, 0); \
    __builtin_amdgcn_global_load_lds(                                         \
        (const __attribute__((address_space(1))) void*)(gb0 + (size_t)64*768 + (T)*32), \
        (__attribute__((address_space(3))) void*)(lb0 + (BUF)*4096 + 2048), 16, 0, 0); \
} while (0)

#define FRAGS(BUF) do {                                                       \
    const ushort* Ab = Al + (BUF)*2048;                                       \
    const ushort* Bb = Bl + (BUF)*4096;                                       \
    _Pragma("unroll")                                                         \
    for (int i = 0; i < 2; ++i)                                               \
        af[i] = *(const bf16x8*)&Ab[(rm + i*16 + col) * 32 + quad * 8];       \
    _Pragma("unroll")                                                         \
    for (int j = 0; j < 4; ++j)                                               \
        bfr[j] = *(const bf16x8*)&Bb[(cn + j*16 + col) * 32 + quad * 8];      \
} while (0)

#define DOMFMA() do {                                                         \
    _Pragma("unroll")                                                         \
    for (int i = 0; i < 2; ++i)                                               \
        _Pragma("unroll")                                                     \
        for (int j = 0; j < 4; ++j)                                           \
            acc[i][j] = __builtin_amdgcn_mfma_f32_16x16x32_bf16(              \
                af[i], bfr[j], acc[i][j], 0, 0, 0);                           \
} while (0)

#define STEP(KK, BUF) do {                                                    \
    FRAGS(BUF);                                                               \
    asm volatile("s_waitcnt lgkmcnt(0)" ::: "memory");                        \
    __builtin_amdgcn_sched_barrier(0);                                        \
    __builtin_amdgcn_s_barrier();      /* all waves done reading buf */       \
    __builtin_amdgcn_sched_barrier(0);                                        \
    GSTAGE((KK) + 3, BUF);             /* overwrite now-free buf */           \
    DOMFMA();                                                                 \
    asm volatile("s_waitcnt vmcnt(6)" ::: "memory");  /* tile KK+1 staged */  \
    __builtin_amdgcn_sched_barrier(0);                                        \
    __builtin_amdgcn_s_barrier();                                             \
    __builtin_amdgcn_sched_barrier(0);                                        \
} while (0)

    bf16x8 af[2], bfr[4];

    GSTAGE(0, 0);
    GSTAGE(1, 1);
    GSTAGE(2, 2);
    asm volatile("s_waitcnt vmcnt(6)" ::: "memory");   // tile 0 staged
    __builtin_amdgcn_sched_barrier(0);
    __builtin_amdgcn_s_barrier();

    for (int kb = 0; kb < 21; kb += 3) {   // kk = 0..20, buf = kk%3
        STEP(kb + 0, 0);
        STEP(kb + 1, 1);
        STEP(kb + 2, 2);
    }
    // epilogue: tiles 21(buf0), 22(buf1), 23(buf2); outstanding 22,23
    FRAGS(0); DOMFMA();
    asm volatile("s_waitcnt vmcnt(3)" ::: "memory");   // tile 22 staged
    __builtin_amdgcn_sched_barrier(0);
    __builtin_amdgcn_s_barrier();
    FRAGS(1); DOMFMA();
    asm volatile("s_waitcnt vmcnt(0)" ::: "memory");   // tile 23 staged
    __builtin_amdgcn_sched_barrier(0);
    __builtin_amdgcn_s_barrier();
    FRAGS(2); DOMFMA();

#undef STEP
#undef DOMFMA
#undef FRAGS
#undef GSTAGE
}

// ---------------------------------------------------------------------------
// Kernel: QKV GEMM (bf16 MFMA) + scatter epilogue.  Grid 1152 (1D),
// XCD panel mapping (unchanged from R8).
// ---------------------------------------------------------------------------
__global__ __launch_bounds__(256) void qkv_mfma_kernel(
    const ushort* __restrict__ xb, const ushort* __restrict__ Wat,
    const float* __restrict__ bias,
    ushort* __restrict__ Qb, ushort* __restrict__ Kb, ushort* __restrict__ Vt)
{
    __shared__ __align__(16) ushort Al[3 * 64 * 32];      // 12 KB
    __shared__ __align__(16) ushort Bl[3 * 128 * 32];     // 24 KB
    __shared__ __align__(16) ushort Tl[4][16][20];

    const int bid = blockIdx.x;
    const int xcd = bid & 7;
    const int idx = bid >> 3;            // 0..143
    const int wk  = xcd * 144 + idx;     // bijective
    const int ni  = wk % 18;
    const int mi  = wk / 18;             // xcd owns mi in [xcd*8, xcd*8+8)
    const int m0 = mi * 64;
    const int n0 = ni * 128;

    f32x4 acc[2][4] = {};
    mfma_gemm64_768(xb, Wat, m0, n0, Al, Bl, acc);

    const int tid  = threadIdx.x;
    const int w    = tid >> 6;
    const int lane = tid & 63;
    const int quad = lane >> 4;
    const int col  = lane & 15;
    const int rm   = (w >> 1) * 32;
    const int cn   = (w & 1) * 64;
    const int part = n0 / CC;
    const float scale = 0.10206207261596575f;

    if (part < 2) {
        #pragma unroll
        for (int i = 0; i < 2; ++i) {
            #pragma unroll
            for (int j = 0; j < 4; ++j) {
                const int n = n0 + cn + j*16 + col;
                const int c = n - part * CC;
                const int h = c / DD, d = c % DD;
                const float bn = bias[n];
                #pragma unroll
                for (int r = 0; r < 4; ++r) {
                    const int m = m0 + rm + i*16 + quad*4 + r;
                    const int b = m >> 11, t = m & 2047;
                    const int bh = b * HH + h;
                    const float v = acc[i][j][r] + bn;
                    if (part == 0) Qb[((size_t)bh*TT + t)*DD + d] = f2bf(v * scale);
                    else           Kb[((size_t)bh*TT + t)*DD + d] = f2bf(v);
                }
            }
        }
    } else {
        #pragma unroll
        for (int i = 0; i < 2; ++i) {
            #pragma unroll
            for (int j = 0; j < 4; ++j) {
                const int n = n0 + cn + j*16 + col;
                const float bn = bias[n];
                ushort4 tv;
                tv.x = f2bf(acc[i][j][0] + bn);
                tv.y = f2bf(acc[i][j][1] + bn);
                tv.z = f2bf(acc[i][j][2] + bn);
                tv.w = f2bf(acc[i][j][3] + bn);
                *(ushort4*)&Tl[w][col][quad * 4] = tv;
                #pragma unroll
                for (int rr = 0; rr < 4; ++rr) {
                    const int c = n0 - 2*CC + cn + j*16 + quad*4 + rr;
                    const int h = c / DD, d = c % DD;
                    const int m = m0 + rm + i*16 + col;
                    const int b = m >> 11, t = m & 2047;
                    Vt[((size_t)(b*HH + h)*DD + d)*TT + t] = Tl[w][quad*4 + rr][col];
                }
            }
        }
    }
}

// ---------------------------------------------------------------------------
// Kernel: flash attention, split-K partials.  R10: revert R9 (direct-global
// regressed: 4x L2 read amplification — each wave re-loaded full K/V tiles;
// cooperative LDS staging is request-count reduction, not redundant caching).
// Back to R4 staged structure + T14 register prefetch: tile t+1's K/V global
// loads issue into regs right after tile t's stage-write barrier, landing
// during the long 2-half compute phase. R1 proved this correct but spilled
// under __launch_bounds__(256,4) (cap 128); here (256,3) caps at 170,
// base 80 + 24 prefetch regs ~= 110 -> no spill expected.
// ---------------------------------------------------------------------------
__device__ const unsigned char RANK2ITEM[40] = {
    60,61,62,63, 56,57,58, 52,53,54, 48,49,50, 44,45,46,
    40,41, 36,37, 32,33, 28,29, 24, 20, 16, 12,
    8,25,42,59,
    4,21,38,55,
    0,17,34,51
};

__global__ __launch_bounds__(256, 3) void attn_mfma_kernel(
    const ushort* __restrict__ Qb, const ushort* __restrict__ Kb,
    const ushort* __restrict__ Vt, ushort* __restrict__ Opart,
    float* __restrict__ Mpart, float* __restrict__ Lpart)
{
    __shared__ __align__(16) ushort Kl[64][104];     // [key][d], +8 pad
    __shared__ __align__(16) ushort Vl[96][72];      // [d][key], +8 pad
    __shared__ __align__(16) ushort Pl[4][16][72];   // per-wave P round-trip

    const int rank = blockIdx.x >> 4;    // 0..39, heavy-first
    const int bh   = blockIdx.x & 15;
    const int code = RANK2ITEM[rank];
    const int qb = code >> 2, ci = code & 3;
    int bse;
    if (qb < 4)       bse = qb;
    else if (qb < 8)  bse = 4  + 2*(qb - 4);
    else if (qb < 12) bse = 12 + 3*(qb - 8);
    else              bse = 24 + 4*(qb - 12);
    const int it = bh * 40 + bse + ci;   // canonical item id

    const int tid  = threadIdx.x;
    const int w    = tid >> 6;
    const int lane = tid & 63;
    const int quad = lane >> 4;
    const int col  = lane & 15;
    const int q0   = qb * 128;

    bf16x8 qf[2][3];
    #pragma unroll
    for (int ih = 0; ih < 2; ++ih) {
        const int qrow = q0 + ih*64 + w*16 + col;
        const ushort* Qp = Qb + ((size_t)bh*TT + qrow)*DD;
        #pragma unroll
        for (int ks = 0; ks < 3; ++ks)
            qf[ih][ks] = *(const bf16x8*)(Qp + ks*32 + quad*8);
    }

    const ushort* Kg = Kb + (size_t)bh*TT*DD;
    const ushort* Vg = Vt + (size_t)bh*DD*TT;

    bf16x8 ones;
    #pragma unroll
    for (int e = 0; e < 8; ++e)
        ones[e] = __builtin_bit_cast(__bf16, (ushort)0x3F80);

    f32x4 O[2][7] = {};                   // [half][c2]; O[ih][6] = l
    float mrow[2][4];
    #pragma unroll
    for (int ih = 0; ih < 2; ++ih)
        #pragma unroll
        for (int r = 0; r < 4; ++r) mrow[ih][r] = -1e30f;

    const int kts = ci * 8;
    const int kte = min(kts + 8, 2*qb + 2);

    // staging address decomposition (constant per thread)
    const int krow = tid / 12, kch = tid % 12;     // + i*256 below
    const int vrow = tid >> 3, vch = tid & 7;

    uint4 kreg[3], vreg[3];
    {   // prologue: prefetch first tile into regs
        const int k0 = kts * 64;
        #pragma unroll
        for (int i = 0; i < 3; ++i) {
            int l = tid + i*256; int row = l / 12, ch = l % 12;
            kreg[i] = *(const uint4*)(Kg + (size_t)(k0 + row)*DD + ch*8);
        }
        #pragma unroll
        for (int i = 0; i < 3; ++i) {
            int l = tid + i*256; int row = l >> 3, ch = l & 7;
            vreg[i] = *(const uint4*)(Vg + (size_t)row*TT + k0 + ch*8);
        }
    }

    for (int kt = kts; kt < kte; ++kt) {
        const int k0 = kt * 64;
        __syncthreads();                  // prev LDS tile fully consumed
        #pragma unroll
        for (int i = 0; i < 3; ++i) {
            int l = tid + i*256; int row = l / 12, ch = l % 12;
            *(uint4*)&Kl[row][ch*8] = kreg[i];
        }
        #pragma unroll
        for (int i = 0; i < 3; ++i) {
            int l = tid + i*256; int row = l >> 3, ch = l & 7;
            *(uint4*)&Vl[row][ch*8] = vreg[i];
        }
        __syncthreads();                  // tile staged

        // T14: issue next tile's global loads; land during compute below
        if (kt + 1 < kte) {
            const int k0n = (kt + 1) * 64;
            #pragma unroll
            for (int i = 0; i < 3; ++i) {
                int l = tid + i*256; int row = l / 12, ch = l % 12;
                kreg[i] = *(const uint4*)(Kg + (size_t)(k0n + row)*DD + ch*8);
            }
            #pragma unroll
            for (int i = 0; i < 3; ++i) {
                int l = tid + i*256; int row = l >> 3, ch = l & 7;
                vreg[i] = *(const uint4*)(Vg + (size_t)row*TT + k0n + ch*8);
            }
        }

        #pragma unroll
        for (int ih = 0; ih < 2; ++ih) {
            f32x4 s[4];
            #pragma unroll
            for (int c = 0; c < 4; ++c) {
                f32x4 a = {0.f, 0.f, 0.f, 0.f};
                #pragma unroll
                for (int ks = 0; ks < 3; ++ks) {
                    bf16x8 bf = *(const bf16x8*)&Kl[c*16 + col][ks*32 + quad*8];
                    a = __builtin_amdgcn_mfma_f32_16x16x32_bf16(qf[ih][ks], bf, a, 0, 0, 0);
                }
                s[c] = a;
            }

            if (kt >= 2*qb + ih) {
                #pragma unroll
                for (int c = 0; c < 4; ++c)
                    #pragma unroll
                    for (int r = 0; r < 4; ++r) {
                        const int qabs = q0 + ih*64 + w*16 + quad*4 + r;
                        const int kabs = k0 + c*16 + col;
                        if (kabs > qabs) s[c][r] = -1e30f;
                    }
            }

            float mx4[4];
            #pragma unroll
            for (int r = 0; r < 4; ++r) {
                float mx = fmaxf(fmaxf(s[0][r], s[1][r]), fmaxf(s[2][r], s[3][r]));
                mx = fmaxf(mx, __shfl_xor(mx, 1, 64));
                mx = fmaxf(mx, __shfl_xor(mx, 2, 64));
                mx = fmaxf(mx, __shfl_xor(mx, 4, 64));
                mx = fmaxf(mx, __shfl_xor(mx, 8, 64));
                mx4[r] = mx;
            }
            const bool grow = (mx4[0] > mrow[ih][0] + 8.f) || (mx4[1] > mrow[ih][1] + 8.f) ||
                              (mx4[2] > mrow[ih][2] + 8.f) || (mx4[3] > mrow[ih][3] + 8.f);
            if (__any(grow)) {
                #pragma unroll
                for (int r = 0; r < 4; ++r) {
                    const float mnew  = fmaxf(mrow[ih][r], mx4[r]);
                    const float alpha = __expf(mrow[ih][r] - mnew);
                    mrow[ih][r] = mnew;
                    #pragma unroll
                    for (int c2 = 0; c2 < 7; ++c2)
                        O[ih][c2][r] *= alpha;
                }
            }

            float ps[4][4];
            #pragma unroll
            for (int r = 0; r < 4; ++r)
                #pragma unroll
                for (int c = 0; c < 4; ++c)
                    ps[c][r] = __expf(s[c][r] - mrow[ih][r]);

            #pragma unroll
            for (int c = 0; c < 4; ++c)
                #pragma unroll
                for (int r = 0; r < 4; ++r)
                    Pl[w][quad*4 + r][c*16 + col] = f2bf(ps[c][r]);

            bf16x8 pf0 = *(const bf16x8*)&Pl[w][col][quad*8];
            bf16x8 pf1 = *(const bf16x8*)&Pl[w][col][32 + quad*8];

            #pragma unroll
            for (int c2 = 0; c2 < 6; ++c2) {
                bf16x8 vb0 = *(const bf16x8*)&Vl[c2*16 + col][quad*8];
                bf16x8 vb1 = *(const bf16x8*)&Vl[c2*16 + col][32 + quad*8];
                O[ih][c2] = __builtin_amdgcn_mfma_f32_16x16x32_bf16(pf0, vb0, O[ih][c2], 0, 0, 0);
                O[ih][c2] = __builtin_amdgcn_mfma_f32_16x16x32_bf16(pf1, vb1, O[ih][c2], 0, 0, 0);
            }
            O[ih][6] = __builtin_amdgcn_mfma_f32_16x16x32_bf16(pf0, ones, O[ih][6], 0, 0, 0);
            O[ih][6] = __builtin_amdgcn_mfma_f32_16x16x32_bf16(pf1, ones, O[ih][6], 0, 0, 0);
        }
    }

    const size_t slot = (size_t)it;
    #pragma unroll
    for (int ih = 0; ih < 2; ++ih) {
        #pragma unroll
        for (int r = 0; r < 4; ++r) {
            const int rl = ih*64 + w*16 + quad*4 + r;
            ushort* Op = Opart + (slot*128 + rl)*DD;
            #pragma unroll
            for (int c2 = 0; c2 < 6; ++c2)
                Op[c2*16 + col] = f2bf(O[ih][c2][r]);
        }
        if (col == 0) {
            #pragma unroll
            for (int r = 0; r < 4; ++r) {
                const int rl = ih*64 + w*16 + quad*4 + r;
                Mpart[slot*128 + rl] = mrow[ih][r];
                Lpart[slot*128 + rl] = O[ih][6][r];
            }
        }
    }
}

// ---------------------------------------------------------------------------
// Kernel: combine split-K partials -> Yb (bf16).  (unchanged)
// ---------------------------------------------------------------------------
__global__ __launch_bounds__(256) void attn_combine_kernel(
    const ushort* __restrict__ Opart, const float* __restrict__ Mpart,
    const float* __restrict__ Lpart, ushort* __restrict__ Yb)
{
    const int x    = blockIdx.x;
    const int bh   = blockIdx.y;
    const int qb   = x >> 1;
    const int half = x & 1;
    const int nC   = (qb >> 2) + 1;
    int bse;
    if (qb < 4)       bse = qb;
    else if (qb < 8)  bse = 4  + 2*(qb - 4);
    else if (qb < 12) bse = 12 + 3*(qb - 8);
    else              bse = 24 + 4*(qb - 12);
    const int item0 = bh * 40 + bse;

    const int tid = threadIdx.x;
    const int row = tid >> 2;
    const int jj  = tid & 3;
    const int rowin = half*64 + row;

    float m[4], f[4];
    float M = -1e30f;
    for (int c = 0; c < nC; ++c) {
        m[c] = Mpart[(size_t)(item0 + c)*128 + rowin];
        M = fmaxf(M, m[c]);
    }
    float L = 0.f;
    for (int c = 0; c < nC; ++c) {
        f[c] = __expf(m[c] - M);
        L += Lpart[(size_t)(item0 + c)*128 + rowin] * f[c];
    }
    const float invL = 1.0f / L;

    float acc[24] = {};
    for (int c = 0; c < nC; ++c) {
        const ushort* Op = Opart + ((size_t)(item0 + c)*128 + rowin)*DD + jj*24;
        const float fc = f[c];
        #pragma unroll
        for (int v = 0; v < 3; ++v) {
            uint4 pk = *(const uint4*)(Op + v*8);
            const ushort* us = (const ushort*)&pk;
            #pragma unroll
            for (int e = 0; e < 8; ++e)
                acc[v*8 + e] += fc * bf2f(us[e]);
        }
    }

    const int q = x*64 + row;
    const int b = bh >> 3, h = bh & 7;
    ushort outv[24];
    #pragma unroll
    for (int e = 0; e < 24; ++e) outv[e] = f2bf(acc[e] * invL);
    ushort* Yp = Yb + ((size_t)b*TT + q)*CC + h*DD + jj*24;
    #pragma unroll
    for (int v = 0; v < 3; ++v)
        *(uint4*)(Yp + v*8) = *(const uint4*)&outv[v*8];
}

// ---------------------------------------------------------------------------
// Kernel: proj GEMM (bf16 MFMA), out = Yb @ W_proj + b_proj, fp32 out.
// Grid 384 (1D), XCD panel mapping (unchanged from R8).
// ---------------------------------------------------------------------------
__global__ __launch_bounds__(256) void proj_mfma_kernel(
    const ushort* __restrict__ Yb, const ushort* __restrict__ Wpt,
    const float* __restrict__ bias, float* __restrict__ out)
{
    __shared__ __align__(16) ushort Al[3 * 64 * 32];
    __shared__ __align__(16) ushort Bl[3 * 128 * 32];

    const int bid = blockIdx.x;
    const int xcd = bid & 7;
    const int idx = bid >> 3;            // 0..47
    const int wk  = xcd * 48 + idx;
    const int ni  = wk % 6;
    const int mi  = wk / 6;              // xcd owns mi in [xcd*8, xcd*8+8)
    const int m0 = mi * 64;
    const int n0 = ni * 128;

    f32x4 acc[2][4] = {};
    mfma_gemm64_768(Yb, Wpt, m0, n0, Al, Bl, acc);

    const int tid  = threadIdx.x;
    const int w    = tid >> 6;
    const int lane = tid & 63;
    const int quad = lane >> 4;
    const int col  = lane & 15;
    const int rm   = (w >> 1) * 32;
    const int cn   = (w & 1) * 64;

    #pragma unroll
    for (int i = 0; i < 2; ++i) {
        #pragma unroll
        for (int j = 0; j < 4; ++j) {
            const int n = n0 + cn + j*16 + col;
            const float bn = bias[n];
            #pragma unroll
            for (int r = 0; r < 4; ++r) {
                const int m = m0 + rm + i*16 + quad*4 + r;
                out[(size_t)m*CC + n] = acc[i][j][r] + bn;
            }
        }
    }
}

extern "C" void kernel_launch(void* const* d_in, const int* in_sizes, int n_in,
                              void* d_out, int out_size, void* d_ws, size_t ws_size,
                              hipStream_t stream) {
    const float* x      = (const float*)d_in[0];
    const float* W_attn = (const float*)d_in[1];
    const float* b_attn = (const float*)d_in[2];
    const float* W_proj = (const float*)d_in[3];
    const float* b_proj = (const float*)d_in[4];
    float* out = (float*)d_out;

    const size_t SLICE   = (size_t)BH * TT * DD;   // 3,145,728
    const size_t OPART_E = (size_t)640 * 128 * DD; // 7,864,320 bf16
    ushort* Opart = (ushort*)d_ws;                 // [640][128][96] bf16
    ushort* xb    = Opart;                         // aliases Opart (xb dead before attn)
    ushort* Qb    = Opart + OPART_E;
    ushort* Kb    = Qb  + SLICE;
    ushort* Vt    = Kb  + SLICE;
    ushort* Yb    = Vt  + SLICE;
    ushort* Wat   = Yb  + SLICE;                   // [2304][768]
    ushort* Wpt   = Wat + (size_t)N3 * CC;         // [768][768]
    float*  Mpart = (float*)(Wpt + (size_t)CC * CC);  // [640][128]
    float*  Lpart = Mpart + (size_t)640 * 128;

    cast_bf16_kernel<<<dim3(SLICE / (256*8)), 256, 0, stream>>>(x, xb);
    tcast_bf16_kernel<<<dim3(N3/64, CC/64), 256, 0, stream>>>(W_attn, Wat, CC, N3);
    tcast_bf16_kernel<<<dim3(CC/64, CC/64), 256, 0, stream>>>(W_proj, Wpt, CC, CC);
    qkv_mfma_kernel<<<dim3(1152), 256, 0, stream>>>(
        xb, Wat, b_attn, Qb, Kb, Vt);
    attn_mfma_kernel<<<dim3(640), 256, 0, stream>>>(
        Qb, Kb, Vt, Opart, Mpart, Lpart);
    attn_combine_kernel<<<dim3(32, BH), 256, 0, stream>>>(
        Opart, Mpart, Lpart, Yb);
    proj_mfma_kernel<<<dim3(384), 256, 0, stream>>>(
        Yb, Wpt, b_proj, out);
}

// Round 11
// 168.951 us; speedup vs baseline: 1.1200x; 1.1200x over previous
//
#include <hip/hip_runtime.h>
#include <hip/hip_bf16.h>

// Problem constants
#define BB 2
#define TT 2048
#define CC 768
#define HH 8
#define DD 96
#define N3 2304   // 3*C
#define BH (BB*HH)

typedef __bf16 bf16x8 __attribute__((ext_vector_type(8)));
typedef float f32x4 __attribute__((ext_vector_type(4)));

__device__ __forceinline__ ushort f2bf(float f) {
    unsigned u = __builtin_bit_cast(unsigned, f);
    u += 0x7fffu + ((u >> 16) & 1u);   // round-to-nearest-even
    return (ushort)(u >> 16);
}
__device__ __forceinline__ float bf2f(ushort u) {
    return __builtin_bit_cast(float, (unsigned)u << 16);
}

// ---------------------------------------------------------------------------
// Fused prep kernel (R11): flat cast x->xb  +  transpose-cast of both
// weight matrices, one dispatch (was 3) — removes 2 launch gaps.
//   bid [0,1536):        cast 2048 fp32 -> bf16 flat
//   bid [1536,1968):     W_attn [768][2304] -> Wat [2304][768]
//   bid [1968,2112):     W_proj [768][768]  -> Wpt [768][768]
// ---------------------------------------------------------------------------
__device__ __forceinline__ void tcast_tile(
    const float* __restrict__ src, ushort* __restrict__ dst,
    int R, int C, int bx, int by, ushort (*t)[66])
{
    const int tid = threadIdx.x;
    const int c0 = bx * 64;
    const int r0 = by * 64;
    const int tx = tid & 63;
    const int ty = tid >> 6;
    #pragma unroll
    for (int i = 0; i < 16; ++i) {
        const int row = ty * 16 + i;
        t[tx][row] = f2bf(src[(size_t)(r0 + row) * C + c0 + tx]);
    }
    __syncthreads();
    #pragma unroll
    for (int i = 0; i < 16; ++i) {
        const int row = ty * 16 + i;
        dst[(size_t)(c0 + row) * R + r0 + tx] = t[row][tx];
    }
}

__global__ __launch_bounds__(256) void prep_kernel(
    const float* __restrict__ x, ushort* __restrict__ xb,
    const float* __restrict__ W_attn, ushort* __restrict__ Wat,
    const float* __restrict__ W_proj, ushort* __restrict__ Wpt)
{
    __shared__ ushort t[64][66];
    const int bid = blockIdx.x;
    if (bid < 1536) {
        const size_t i = ((size_t)bid * 256 + threadIdx.x) * 8;
        float4 a = *(const float4*)&x[i];
        float4 b = *(const float4*)&x[i + 4];
        ushort tmp[8] = {f2bf(a.x), f2bf(a.y), f2bf(a.z), f2bf(a.w),
                         f2bf(b.x), f2bf(b.y), f2bf(b.z), f2bf(b.w)};
        *(uint4*)&xb[i] = *(const uint4*)tmp;
    } else if (bid < 1536 + 432) {
        const int tb = bid - 1536;           // W_attn: grid was (36, 12)
        tcast_tile(W_attn, Wat, CC, N3, tb % 36, tb / 36, t);
    } else {
        const int tb = bid - 1968;           // W_proj: grid was (12, 12)
        tcast_tile(W_proj, Wpt, CC, CC, tb % 12, tb / 12, t);
    }
}

// ---------------------------------------------------------------------------
// Shared MFMA GEMM mainloop (R8 state, frozen): 64x128 tile, BK=32, K=768,
// triple-buffered counted-vmcnt pipeline.
// ---------------------------------------------------------------------------
__device__ __forceinline__ void mfma_gemm64_768(
    const ushort* __restrict__ A, const ushort* __restrict__ Bt,
    int m0, int n0, ushort* Al, ushort* Bl, f32x4 (&acc)[2][4])
{
    const int tid  = threadIdx.x;
    const int w    = tid >> 6;
    const int lane = tid & 63;
    const int quad = lane >> 4;
    const int col  = lane & 15;
    const int rm   = (w >> 1) * 32;     // wave row offset within 64
    const int cn   = (w & 1) * 64;      // wave col offset within 128

    const int row_s = tid >> 2, sub = tid & 3;   // 64 rows x 4 chunks
    const ushort* ga0 = A  + (size_t)(m0 + row_s) * 768 + sub * 8;
    const ushort* gb0 = Bt + (size_t)(n0 + row_s) * 768 + sub * 8;
    ushort* la0 = Al + tid * 8;         // linear within one A buffer (2048 el)
    ushort* lb0 = Bl + tid * 8;         // linear within one B buffer (4096 el)

#define GSTAGE(T, BUF) do {                                                   \
    __builtin_amdgcn_global_load_lds(                                         \
        (const __attribute__((address_space(1))) void*)(ga0 + (T)*32),        \
        (__attribute__((address_space(3))) void*)(la0 + (BUF)*2048), 16, 0, 0); \
    __builtin_amdgcn_global_load_lds(                                         \
        (const __attribute__((address_space(1))) void*)(gb0 + (T)*32),        \
        (__attribute__((address_space(3))) void*)(lb0 + (BUF)*4096), 16, 0, 0); \
    __builtin_amdgcn_global_load_lds(                                         \
        (const __attribute__((address_space(1))) void*)(gb0 + (size_t)64*768 + (T)*32), \
        (__attribute__((address_space(3))) void*)(lb0 + (BUF)*4096 + 2048), 16, 0, 0); \
} while (0)

#define FRAGS(BUF) do {                                                       \
    const ushort* Ab = Al + (BUF)*2048;                                       \
    const ushort* Bb = Bl + (BUF)*4096;                                       \
    _Pragma("unroll")                                                         \
    for (int i = 0; i < 2; ++i)                                               \
        af[i] = *(const bf16x8*)&Ab[(rm + i*16 + col) * 32 + quad * 8];       \
    _Pragma("unroll")                                                         \
    for (int j = 0; j < 4; ++j)                                               \
        bfr[j] = *(const bf16x8*)&Bb[(cn + j*16 + col) * 32 + quad * 8];      \
} while (0)

#define DOMFMA() do {                                                         \
    _Pragma("unroll")                                                         \
    for (int i = 0; i < 2; ++i)                                               \
        _Pragma("unroll")                                                     \
        for (int j = 0; j < 4; ++j)                                           \
            acc[i][j] = __builtin_amdgcn_mfma_f32_16x16x32_bf16(              \
                af[i], bfr[j], acc[i][j], 0, 0, 0);                           \
} while (0)

#define STEP(KK, BUF) do {                                                    \
    FRAGS(BUF);                                                               \
    asm volatile("s_waitcnt lgkmcnt(0)" ::: "memory");                        \
    __builtin_amdgcn_sched_barrier(0);                                        \
    __builtin_amdgcn_s_barrier();      /* all waves done reading buf */       \
    __builtin_amdgcn_sched_barrier(0);                                        \
    GSTAGE((KK) + 3, BUF);             /* overwrite now-free buf */           \
    DOMFMA();                                                                 \
    asm volatile("s_waitcnt vmcnt(6)" ::: "memory");  /* tile KK+1 staged */  \
    __builtin_amdgcn_sched_barrier(0);                                        \
    __builtin_amdgcn_s_barrier();                                             \
    __builtin_amdgcn_sched_barrier(0);                                        \
} while (0)

    bf16x8 af[2], bfr[4];

    GSTAGE(0, 0);
    GSTAGE(1, 1);
    GSTAGE(2, 2);
    asm volatile("s_waitcnt vmcnt(6)" ::: "memory");   // tile 0 staged
    __builtin_amdgcn_sched_barrier(0);
    __builtin_amdgcn_s_barrier();

    for (int kb = 0; kb < 21; kb += 3) {   // kk = 0..20, buf = kk%3
        STEP(kb + 0, 0);
        STEP(kb + 1, 1);
        STEP(kb + 2, 2);
    }
    // epilogue: tiles 21(buf0), 22(buf1), 23(buf2); outstanding 22,23
    FRAGS(0); DOMFMA();
    asm volatile("s_waitcnt vmcnt(3)" ::: "memory");   // tile 22 staged
    __builtin_amdgcn_sched_barrier(0);
    __builtin_amdgcn_s_barrier();
    FRAGS(1); DOMFMA();
    asm volatile("s_waitcnt vmcnt(0)" ::: "memory");   // tile 23 staged
    __builtin_amdgcn_sched_barrier(0);
    __builtin_amdgcn_s_barrier();
    FRAGS(2); DOMFMA();

#undef STEP
#undef DOMFMA
#undef FRAGS
#undef GSTAGE
}

// ---------------------------------------------------------------------------
// Kernel: QKV GEMM (bf16 MFMA) + scatter epilogue.  Grid 1152 (1D),
// XCD panel mapping (unchanged from R8).
// ---------------------------------------------------------------------------
__global__ __launch_bounds__(256) void qkv_mfma_kernel(
    const ushort* __restrict__ xb, const ushort* __restrict__ Wat,
    const float* __restrict__ bias,
    ushort* __restrict__ Qb, ushort* __restrict__ Kb, ushort* __restrict__ Vt)
{
    __shared__ __align__(16) ushort Al[3 * 64 * 32];      // 12 KB
    __shared__ __align__(16) ushort Bl[3 * 128 * 32];     // 24 KB
    __shared__ __align__(16) ushort Tl[4][16][20];

    const int bid = blockIdx.x;
    const int xcd = bid & 7;
    const int idx = bid >> 3;            // 0..143
    const int wk  = xcd * 144 + idx;     // bijective
    const int ni  = wk % 18;
    const int mi  = wk / 18;             // xcd owns mi in [xcd*8, xcd*8+8)
    const int m0 = mi * 64;
    const int n0 = ni * 128;

    f32x4 acc[2][4] = {};
    mfma_gemm64_768(xb, Wat, m0, n0, Al, Bl, acc);

    const int tid  = threadIdx.x;
    const int w    = tid >> 6;
    const int lane = tid & 63;
    const int quad = lane >> 4;
    const int col  = lane & 15;
    const int rm   = (w >> 1) * 32;
    const int cn   = (w & 1) * 64;
    const int part = n0 / CC;
    const float scale = 0.10206207261596575f;

    if (part < 2) {
        #pragma unroll
        for (int i = 0; i < 2; ++i) {
            #pragma unroll
            for (int j = 0; j < 4; ++j) {
                const int n = n0 + cn + j*16 + col;
                const int c = n - part * CC;
                const int h = c / DD, d = c % DD;
                const float bn = bias[n];
                #pragma unroll
                for (int r = 0; r < 4; ++r) {
                    const int m = m0 + rm + i*16 + quad*4 + r;
                    const int b = m >> 11, t = m & 2047;
                    const int bh = b * HH + h;
                    const float v = acc[i][j][r] + bn;
                    if (part == 0) Qb[((size_t)bh*TT + t)*DD + d] = f2bf(v * scale);
                    else           Kb[((size_t)bh*TT + t)*DD + d] = f2bf(v);
                }
            }
        }
    } else {
        #pragma unroll
        for (int i = 0; i < 2; ++i) {
            #pragma unroll
            for (int j = 0; j < 4; ++j) {
                const int n = n0 + cn + j*16 + col;
                const float bn = bias[n];
                ushort4 tv;
                tv.x = f2bf(acc[i][j][0] + bn);
                tv.y = f2bf(acc[i][j][1] + bn);
                tv.z = f2bf(acc[i][j][2] + bn);
                tv.w = f2bf(acc[i][j][3] + bn);
                *(ushort4*)&Tl[w][col][quad * 4] = tv;
                #pragma unroll
                for (int rr = 0; rr < 4; ++rr) {
                    const int c = n0 - 2*CC + cn + j*16 + quad*4 + rr;
                    const int h = c / DD, d = c % DD;
                    const int m = m0 + rm + i*16 + col;
                    const int b = m >> 11, t = m & 2047;
                    Vt[((size_t)(b*HH + h)*DD + d)*TT + t] = Tl[w][quad*4 + rr][col];
                }
            }
        }
    }
}

// ---------------------------------------------------------------------------
// Kernel: flash attention, split-K partials. (R8 state restored: plain
// cooperative staged K/V -> LDS. T14 reg-prefetch removed permanently —
// spilled to scratch in BOTH attempts (R1: WRITE 186MB, R10: WRITE 78MB);
// compiler refuses to keep uint4[3]x2 live across barriers+compute here.)
// Q-tile = 128 rows/block; 40 items/bh, 640 blocks, all co-resident.
// ---------------------------------------------------------------------------
__device__ const unsigned char RANK2ITEM[40] = {
    60,61,62,63, 56,57,58, 52,53,54, 48,49,50, 44,45,46,
    40,41, 36,37, 32,33, 28,29, 24, 20, 16, 12,
    8,25,42,59,
    4,21,38,55,
    0,17,34,51
};

__global__ __launch_bounds__(256, 3) void attn_mfma_kernel(
    const ushort* __restrict__ Qb, const ushort* __restrict__ Kb,
    const ushort* __restrict__ Vt, ushort* __restrict__ Opart,
    float* __restrict__ Mpart, float* __restrict__ Lpart)
{
    __shared__ __align__(16) ushort Kl[64][104];     // [key][d], +8 pad
    __shared__ __align__(16) ushort Vl[96][72];      // [d][key], +8 pad
    __shared__ __align__(16) ushort Pl[4][16][72];   // per-wave P round-trip

    const int rank = blockIdx.x >> 4;    // 0..39, heavy-first
    const int bh   = blockIdx.x & 15;
    const int code = RANK2ITEM[rank];
    const int qb = code >> 2, ci = code & 3;
    int bse;
    if (qb < 4)       bse = qb;
    else if (qb < 8)  bse = 4  + 2*(qb - 4);
    else if (qb < 12) bse = 12 + 3*(qb - 8);
    else              bse = 24 + 4*(qb - 12);
    const int it = bh * 40 + bse + ci;   // canonical item id

    const int tid  = threadIdx.x;
    const int w    = tid >> 6;
    const int lane = tid & 63;
    const int quad = lane >> 4;
    const int col  = lane & 15;
    const int q0   = qb * 128;

    bf16x8 qf[2][3];
    #pragma unroll
    for (int ih = 0; ih < 2; ++ih) {
        const int qrow = q0 + ih*64 + w*16 + col;
        const ushort* Qp = Qb + ((size_t)bh*TT + qrow)*DD;
        #pragma unroll
        for (int ks = 0; ks < 3; ++ks)
            qf[ih][ks] = *(const bf16x8*)(Qp + ks*32 + quad*8);
    }

    const ushort* Kg = Kb + (size_t)bh*TT*DD;
    const ushort* Vg = Vt + (size_t)bh*DD*TT;

    bf16x8 ones;
    #pragma unroll
    for (int e = 0; e < 8; ++e)
        ones[e] = __builtin_bit_cast(__bf16, (ushort)0x3F80);

    f32x4 O[2][7] = {};                   // [half][c2]; O[ih][6] = l
    float mrow[2][4];
    #pragma unroll
    for (int ih = 0; ih < 2; ++ih)
        #pragma unroll
        for (int r = 0; r < 4; ++r) mrow[ih][r] = -1e30f;

    const int kts = ci * 8;
    const int kte = min(kts + 8, 2*qb + 2);

    for (int kt = kts; kt < kte; ++kt) {
        const int k0 = kt * 64;
        __syncthreads();
        #pragma unroll
        for (int i = 0; i < 3; ++i) {
            int l = tid + i*256;
            int row = l / 12, ch = l % 12;
            uint4 vv = *(const uint4*)(Kg + (size_t)(k0 + row)*DD + ch*8);
            *(uint4*)&Kl[row][ch*8] = vv;
        }
        #pragma unroll
        for (int i = 0; i < 3; ++i) {
            int l = tid + i*256;
            int row = l / 8, ch = l % 8;
            uint4 vv = *(const uint4*)(Vg + (size_t)row*TT + k0 + ch*8);
            *(uint4*)&Vl[row][ch*8] = vv;
        }
        __syncthreads();

        #pragma unroll
        for (int ih = 0; ih < 2; ++ih) {
            f32x4 s[4];
            #pragma unroll
            for (int c = 0; c < 4; ++c) {
                f32x4 a = {0.f, 0.f, 0.f, 0.f};
                #pragma unroll
                for (int ks = 0; ks < 3; ++ks) {
                    bf16x8 bf = *(const bf16x8*)&Kl[c*16 + col][ks*32 + quad*8];
                    a = __builtin_amdgcn_mfma_f32_16x16x32_bf16(qf[ih][ks], bf, a, 0, 0, 0);
                }
                s[c] = a;
            }

            if (kt >= 2*qb + ih) {
                #pragma unroll
                for (int c = 0; c < 4; ++c)
                    #pragma unroll
                    for (int r = 0; r < 4; ++r) {
                        const int qabs = q0 + ih*64 + w*16 + quad*4 + r;
                        const int kabs = k0 + c*16 + col;
                        if (kabs > qabs) s[c][r] = -1e30f;
                    }
            }

            float mx4[4];
            #pragma unroll
            for (int r = 0; r < 4; ++r) {
                float mx = fmaxf(fmaxf(s[0][r], s[1][r]), fmaxf(s[2][r], s[3][r]));
                mx = fmaxf(mx, __shfl_xor(mx, 1, 64));
                mx = fmaxf(mx, __shfl_xor(mx, 2, 64));
                mx = fmaxf(mx, __shfl_xor(mx, 4, 64));
                mx = fmaxf(mx, __shfl_xor(mx, 8, 64));
                mx4[r] = mx;
            }
            const bool grow = (mx4[0] > mrow[ih][0] + 8.f) || (mx4[1] > mrow[ih][1] + 8.f) ||
                              (mx4[2] > mrow[ih][2] + 8.f) || (mx4[3] > mrow[ih][3] + 8.f);
            if (__any(grow)) {
                #pragma unroll
                for (int r = 0; r < 4; ++r) {
                    const float mnew  = fmaxf(mrow[ih][r], mx4[r]);
                    const float alpha = __expf(mrow[ih][r] - mnew);
                    mrow[ih][r] = mnew;
                    #pragma unroll
                    for (int c2 = 0; c2 < 7; ++c2)
                        O[ih][c2][r] *= alpha;
                }
            }

            float ps[4][4];
            #pragma unroll
            for (int r = 0; r < 4; ++r)
                #pragma unroll
                for (int c = 0; c < 4; ++c)
                    ps[c][r] = __expf(s[c][r] - mrow[ih][r]);

            #pragma unroll
            for (int c = 0; c < 4; ++c)
                #pragma unroll
                for (int r = 0; r < 4; ++r)
                    Pl[w][quad*4 + r][c*16 + col] = f2bf(ps[c][r]);

            bf16x8 pf0 = *(const bf16x8*)&Pl[w][col][quad*8];
            bf16x8 pf1 = *(const bf16x8*)&Pl[w][col][32 + quad*8];

            #pragma unroll
            for (int c2 = 0; c2 < 6; ++c2) {
                bf16x8 vb0 = *(const bf16x8*)&Vl[c2*16 + col][quad*8];
                bf16x8 vb1 = *(const bf16x8*)&Vl[c2*16 + col][32 + quad*8];
                O[ih][c2] = __builtin_amdgcn_mfma_f32_16x16x32_bf16(pf0, vb0, O[ih][c2], 0, 0, 0);
                O[ih][c2] = __builtin_amdgcn_mfma_f32_16x16x32_bf16(pf1, vb1, O[ih][c2], 0, 0, 0);
            }
            O[ih][6] = __builtin_amdgcn_mfma_f32_16x16x32_bf16(pf0, ones, O[ih][6], 0, 0, 0);
            O[ih][6] = __builtin_amdgcn_mfma_f32_16x16x32_bf16(pf1, ones, O[ih][6], 0, 0, 0);
        }
    }

    const size_t slot = (size_t)it;
    #pragma unroll
    for (int ih = 0; ih < 2; ++ih) {
        #pragma unroll
        for (int r = 0; r < 4; ++r) {
            const int rl = ih*64 + w*16 + quad*4 + r;
            ushort* Op = Opart + (slot*128 + rl)*DD;
            #pragma unroll
            for (int c2 = 0; c2 < 6; ++c2)
                Op[c2*16 + col] = f2bf(O[ih][c2][r]);
        }
        if (col == 0) {
            #pragma unroll
            for (int r = 0; r < 4; ++r) {
                const int rl = ih*64 + w*16 + quad*4 + r;
                Mpart[slot*128 + rl] = mrow[ih][r];
                Lpart[slot*128 + rl] = O[ih][6][r];
            }
        }
    }
}

// ---------------------------------------------------------------------------
// Kernel: combine split-K partials -> Yb (bf16).  (unchanged)
// ---------------------------------------------------------------------------
__global__ __launch_bounds__(256) void attn_combine_kernel(
    const ushort* __restrict__ Opart, const float* __restrict__ Mpart,
    const float* __restrict__ Lpart, ushort* __restrict__ Yb)
{
    const int x    = blockIdx.x;
    const int bh   = blockIdx.y;
    const int qb   = x >> 1;
    const int half = x & 1;
    const int nC   = (qb >> 2) + 1;
    int bse;
    if (qb < 4)       bse = qb;
    else if (qb < 8)  bse = 4  + 2*(qb - 4);
    else if (qb < 12) bse = 12 + 3*(qb - 8);
    else              bse = 24 + 4*(qb - 12);
    const int item0 = bh * 40 + bse;

    const int tid = threadIdx.x;
    const int row = tid >> 2;
    const int jj  = tid & 3;
    const int rowin = half*64 + row;

    float m[4], f[4];
    float M = -1e30f;
    for (int c = 0; c < nC; ++c) {
        m[c] = Mpart[(size_t)(item0 + c)*128 + rowin];
        M = fmaxf(M, m[c]);
    }
    float L = 0.f;
    for (int c = 0; c < nC; ++c) {
        f[c] = __expf(m[c] - M);
        L += Lpart[(size_t)(item0 + c)*128 + rowin] * f[c];
    }
    const float invL = 1.0f / L;

    float acc[24] = {};
    for (int c = 0; c < nC; ++c) {
        const ushort* Op = Opart + ((size_t)(item0 + c)*128 + rowin)*DD + jj*24;
        const float fc = f[c];
        #pragma unroll
        for (int v = 0; v < 3; ++v) {
            uint4 pk = *(const uint4*)(Op + v*8);
            const ushort* us = (const ushort*)&pk;
            #pragma unroll
            for (int e = 0; e < 8; ++e)
                acc[v*8 + e] += fc * bf2f(us[e]);
        }
    }

    const int q = x*64 + row;
    const int b = bh >> 3, h = bh & 7;
    ushort outv[24];
    #pragma unroll
    for (int e = 0; e < 24; ++e) outv[e] = f2bf(acc[e] * invL);
    ushort* Yp = Yb + ((size_t)b*TT + q)*CC + h*DD + jj*24;
    #pragma unroll
    for (int v = 0; v < 3; ++v)
        *(uint4*)(Yp + v*8) = *(const uint4*)&outv[v*8];
}

// ---------------------------------------------------------------------------
// Kernel: proj GEMM (bf16 MFMA), out = Yb @ W_proj + b_proj, fp32 out.
// Grid 384 (1D), XCD panel mapping (unchanged from R8).
// ---------------------------------------------------------------------------
__global__ __launch_bounds__(256) void proj_mfma_kernel(
    const ushort* __restrict__ Yb, const ushort* __restrict__ Wpt,
    const float* __restrict__ bias, float* __restrict__ out)
{
    __shared__ __align__(16) ushort Al[3 * 64 * 32];
    __shared__ __align__(16) ushort Bl[3 * 128 * 32];

    const int bid = blockIdx.x;
    const int xcd = bid & 7;
    const int idx = bid >> 3;            // 0..47
    const int wk  = xcd * 48 + idx;
    const int ni  = wk % 6;
    const int mi  = wk / 6;              // xcd owns mi in [xcd*8, xcd*8+8)
    const int m0 = mi * 64;
    const int n0 = ni * 128;

    f32x4 acc[2][4] = {};
    mfma_gemm64_768(Yb, Wpt, m0, n0, Al, Bl, acc);

    const int tid  = threadIdx.x;
    const int w    = tid >> 6;
    const int lane = tid & 63;
    const int quad = lane >> 4;
    const int col  = lane & 15;
    const int rm   = (w >> 1) * 32;
    const int cn   = (w & 1) * 64;

    #pragma unroll
    for (int i = 0; i < 2; ++i) {
        #pragma unroll
        for (int j = 0; j < 4; ++j) {
            const int n = n0 + cn + j*16 + col;
            const float bn = bias[n];
            #pragma unroll
            for (int r = 0; r < 4; ++r) {
                const int m = m0 + rm + i*16 + quad*4 + r;
                out[(size_t)m*CC + n] = acc[i][j][r] + bn;
            }
        }
    }
}

extern "C" void kernel_launch(void* const* d_in, const int* in_sizes, int n_in,
                              void* d_out, int out_size, void* d_ws, size_t ws_size,
                              hipStream_t stream) {
    const float* x      = (const float*)d_in[0];
    const float* W_attn = (const float*)d_in[1];
    const float* b_attn = (const float*)d_in[2];
    const float* W_proj = (const float*)d_in[3];
    const float* b_proj = (const float*)d_in[4];
    float* out = (float*)d_out;

    const size_t SLICE   = (size_t)BH * TT * DD;   // 3,145,728
    const size_t OPART_E = (size_t)640 * 128 * DD; // 7,864,320 bf16
    ushort* Opart = (ushort*)d_ws;                 // [640][128][96] bf16
    ushort* xb    = Opart;                         // aliases Opart (xb dead before attn)
    ushort* Qb    = Opart + OPART_E;
    ushort* Kb    = Qb  + SLICE;
    ushort* Vt    = Kb  + SLICE;
    ushort* Yb    = Vt  + SLICE;
    ushort* Wat   = Yb  + SLICE;                   // [2304][768]
    ushort* Wpt   = Wat + (size_t)N3 * CC;         // [768][768]
    float*  Mpart = (float*)(Wpt + (size_t)CC * CC);  // [640][128]
    float*  Lpart = Mpart + (size_t)640 * 128;

    prep_kernel<<<dim3(2112), 256, 0, stream>>>(x, xb, W_attn, Wat, W_proj, Wpt);
    qkv_mfma_kernel<<<dim3(1152), 256, 0, stream>>>(
        xb, Wat, b_attn, Qb, Kb, Vt);
    attn_mfma_kernel<<<dim3(640), 256, 0, stream>>>(
        Qb, Kb, Vt, Opart, Mpart, Lpart);
    attn_combine_kernel<<<dim3(32, BH), 256, 0, stream>>>(
        Opart, Mpart, Lpart, Yb);
    proj_mfma_kernel<<<dim3(384), 256, 0, stream>>>(
        Yb, Wpt, b_proj, out);
}

// Round 12
// 168.071 us; speedup vs baseline: 1.1258x; 1.0052x over previous
//
#include <hip/hip_runtime.h>
#include <hip/hip_bf16.h>

// Problem constants
#define BB 2
#define TT 2048
#define CC 768
#define HH 8
#define DD 96
#define N3 2304   // 3*C
#define BH (BB*HH)

typedef __bf16 bf16x8 __attribute__((ext_vector_type(8)));
typedef float f32x4 __attribute__((ext_vector_type(4)));

__device__ __forceinline__ ushort f2bf(float f) {
    unsigned u = __builtin_bit_cast(unsigned, f);
    u += 0x7fffu + ((u >> 16) & 1u);   // round-to-nearest-even
    return (ushort)(u >> 16);
}
__device__ __forceinline__ float bf2f(ushort u) {
    return __builtin_bit_cast(float, (unsigned)u << 16);
}

// ---------------------------------------------------------------------------
// Fused prep kernel (R11): flat cast x->xb  +  transpose-cast of both
// weight matrices, one dispatch.
// ---------------------------------------------------------------------------
__device__ __forceinline__ void tcast_tile(
    const float* __restrict__ src, ushort* __restrict__ dst,
    int R, int C, int bx, int by, ushort (*t)[66])
{
    const int tid = threadIdx.x;
    const int c0 = bx * 64;
    const int r0 = by * 64;
    const int tx = tid & 63;
    const int ty = tid >> 6;
    #pragma unroll
    for (int i = 0; i < 16; ++i) {
        const int row = ty * 16 + i;
        t[tx][row] = f2bf(src[(size_t)(r0 + row) * C + c0 + tx]);
    }
    __syncthreads();
    #pragma unroll
    for (int i = 0; i < 16; ++i) {
        const int row = ty * 16 + i;
        dst[(size_t)(c0 + row) * R + r0 + tx] = t[row][tx];
    }
}

__global__ __launch_bounds__(256) void prep_kernel(
    const float* __restrict__ x, ushort* __restrict__ xb,
    const float* __restrict__ W_attn, ushort* __restrict__ Wat,
    const float* __restrict__ W_proj, ushort* __restrict__ Wpt)
{
    __shared__ ushort t[64][66];
    const int bid = blockIdx.x;
    if (bid < 1536) {
        const size_t i = ((size_t)bid * 256 + threadIdx.x) * 8;
        float4 a = *(const float4*)&x[i];
        float4 b = *(const float4*)&x[i + 4];
        ushort tmp[8] = {f2bf(a.x), f2bf(a.y), f2bf(a.z), f2bf(a.w),
                         f2bf(b.x), f2bf(b.y), f2bf(b.z), f2bf(b.w)};
        *(uint4*)&xb[i] = *(const uint4*)tmp;
    } else if (bid < 1536 + 432) {
        const int tb = bid - 1536;           // W_attn: (36, 12)
        tcast_tile(W_attn, Wat, CC, N3, tb % 36, tb / 36, t);
    } else {
        const int tb = bid - 1968;           // W_proj: (12, 12)
        tcast_tile(W_proj, Wpt, CC, CC, tb % 12, tb / 12, t);
    }
}

// ---------------------------------------------------------------------------
// Shared MFMA GEMM mainloop (R8 state, frozen): 64x128 tile, BK=32, K=768,
// triple-buffered counted-vmcnt pipeline.
// ---------------------------------------------------------------------------
__device__ __forceinline__ void mfma_gemm64_768(
    const ushort* __restrict__ A, const ushort* __restrict__ Bt,
    int m0, int n0, ushort* Al, ushort* Bl, f32x4 (&acc)[2][4])
{
    const int tid  = threadIdx.x;
    const int w    = tid >> 6;
    const int lane = tid & 63;
    const int quad = lane >> 4;
    const int col  = lane & 15;
    const int rm   = (w >> 1) * 32;     // wave row offset within 64
    const int cn   = (w & 1) * 64;      // wave col offset within 128

    const int row_s = tid >> 2, sub = tid & 3;   // 64 rows x 4 chunks
    const ushort* ga0 = A  + (size_t)(m0 + row_s) * 768 + sub * 8;
    const ushort* gb0 = Bt + (size_t)(n0 + row_s) * 768 + sub * 8;
    ushort* la0 = Al + tid * 8;         // linear within one A buffer (2048 el)
    ushort* lb0 = Bl + tid * 8;         // linear within one B buffer (4096 el)

#define GSTAGE(T, BUF) do {                                                   \
    __builtin_amdgcn_global_load_lds(                                         \
        (const __attribute__((address_space(1))) void*)(ga0 + (T)*32),        \
        (__attribute__((address_space(3))) void*)(la0 + (BUF)*2048), 16, 0, 0); \
    __builtin_amdgcn_global_load_lds(                                         \
        (const __attribute__((address_space(1))) void*)(gb0 + (T)*32),        \
        (__attribute__((address_space(3))) void*)(lb0 + (BUF)*4096), 16, 0, 0); \
    __builtin_amdgcn_global_load_lds(                                         \
        (const __attribute__((address_space(1))) void*)(gb0 + (size_t)64*768 + (T)*32), \
        (__attribute__((address_space(3))) void*)(lb0 + (BUF)*4096 + 2048), 16, 0, 0); \
} while (0)

#define FRAGS(BUF) do {                                                       \
    const ushort* Ab = Al + (BUF)*2048;                                       \
    const ushort* Bb = Bl + (BUF)*4096;                                       \
    _Pragma("unroll")                                                         \
    for (int i = 0; i < 2; ++i)                                               \
        af[i] = *(const bf16x8*)&Ab[(rm + i*16 + col) * 32 + quad * 8];       \
    _Pragma("unroll")                                                         \
    for (int j = 0; j < 4; ++j)                                               \
        bfr[j] = *(const bf16x8*)&Bb[(cn + j*16 + col) * 32 + quad * 8];      \
} while (0)

#define DOMFMA() do {                                                         \
    _Pragma("unroll")                                                         \
    for (int i = 0; i < 2; ++i)                                               \
        _Pragma("unroll")                                                     \
        for (int j = 0; j < 4; ++j)                                           \
            acc[i][j] = __builtin_amdgcn_mfma_f32_16x16x32_bf16(              \
                af[i], bfr[j], acc[i][j], 0, 0, 0);                           \
} while (0)

#define STEP(KK, BUF) do {                                                    \
    FRAGS(BUF);                                                               \
    asm volatile("s_waitcnt lgkmcnt(0)" ::: "memory");                        \
    __builtin_amdgcn_sched_barrier(0);                                        \
    __builtin_amdgcn_s_barrier();      /* all waves done reading buf */       \
    __builtin_amdgcn_sched_barrier(0);                                        \
    GSTAGE((KK) + 3, BUF);             /* overwrite now-free buf */           \
    DOMFMA();                                                                 \
    asm volatile("s_waitcnt vmcnt(6)" ::: "memory");  /* tile KK+1 staged */  \
    __builtin_amdgcn_sched_barrier(0);                                        \
    __builtin_amdgcn_s_barrier();                                             \
    __builtin_amdgcn_sched_barrier(0);                                        \
} while (0)

    bf16x8 af[2], bfr[4];

    GSTAGE(0, 0);
    GSTAGE(1, 1);
    GSTAGE(2, 2);
    asm volatile("s_waitcnt vmcnt(6)" ::: "memory");   // tile 0 staged
    __builtin_amdgcn_sched_barrier(0);
    __builtin_amdgcn_s_barrier();

    for (int kb = 0; kb < 21; kb += 3) {   // kk = 0..20, buf = kk%3
        STEP(kb + 0, 0);
        STEP(kb + 1, 1);
        STEP(kb + 2, 2);
    }
    // epilogue: tiles 21(buf0), 22(buf1), 23(buf2); outstanding 22,23
    FRAGS(0); DOMFMA();
    asm volatile("s_waitcnt vmcnt(3)" ::: "memory");   // tile 22 staged
    __builtin_amdgcn_sched_barrier(0);
    __builtin_amdgcn_s_barrier();
    FRAGS(1); DOMFMA();
    asm volatile("s_waitcnt vmcnt(0)" ::: "memory");   // tile 23 staged
    __builtin_amdgcn_sched_barrier(0);
    __builtin_amdgcn_s_barrier();
    FRAGS(2); DOMFMA();

#undef STEP
#undef DOMFMA
#undef FRAGS
#undef GSTAGE
}

// ---------------------------------------------------------------------------
// Kernel: QKV GEMM (bf16 MFMA) + scatter epilogue.  Grid 1152 (1D),
// XCD panel mapping (unchanged from R8).
// ---------------------------------------------------------------------------
__global__ __launch_bounds__(256) void qkv_mfma_kernel(
    const ushort* __restrict__ xb, const ushort* __restrict__ Wat,
    const float* __restrict__ bias,
    ushort* __restrict__ Qb, ushort* __restrict__ Kb, ushort* __restrict__ Vt)
{
    __shared__ __align__(16) ushort Al[3 * 64 * 32];      // 12 KB
    __shared__ __align__(16) ushort Bl[3 * 128 * 32];     // 24 KB
    __shared__ __align__(16) ushort Tl[4][16][20];

    const int bid = blockIdx.x;
    const int xcd = bid & 7;
    const int idx = bid >> 3;            // 0..143
    const int wk  = xcd * 144 + idx;     // bijective
    const int ni  = wk % 18;
    const int mi  = wk / 18;             // xcd owns mi in [xcd*8, xcd*8+8)
    const int m0 = mi * 64;
    const int n0 = ni * 128;

    f32x4 acc[2][4] = {};
    mfma_gemm64_768(xb, Wat, m0, n0, Al, Bl, acc);

    const int tid  = threadIdx.x;
    const int w    = tid >> 6;
    const int lane = tid & 63;
    const int quad = lane >> 4;
    const int col  = lane & 15;
    const int rm   = (w >> 1) * 32;
    const int cn   = (w & 1) * 64;
    const int part = n0 / CC;
    const float scale = 0.10206207261596575f;

    if (part < 2) {
        #pragma unroll
        for (int i = 0; i < 2; ++i) {
            #pragma unroll
            for (int j = 0; j < 4; ++j) {
                const int n = n0 + cn + j*16 + col;
                const int c = n - part * CC;
                const int h = c / DD, d = c % DD;
                const float bn = bias[n];
                #pragma unroll
                for (int r = 0; r < 4; ++r) {
                    const int m = m0 + rm + i*16 + quad*4 + r;
                    const int b = m >> 11, t = m & 2047;
                    const int bh = b * HH + h;
                    const float v = acc[i][j][r] + bn;
                    if (part == 0) Qb[((size_t)bh*TT + t)*DD + d] = f2bf(v * scale);
                    else           Kb[((size_t)bh*TT + t)*DD + d] = f2bf(v);
                }
            }
        }
    } else {
        #pragma unroll
        for (int i = 0; i < 2; ++i) {
            #pragma unroll
            for (int j = 0; j < 4; ++j) {
                const int n = n0 + cn + j*16 + col;
                const float bn = bias[n];
                ushort4 tv;
                tv.x = f2bf(acc[i][j][0] + bn);
                tv.y = f2bf(acc[i][j][1] + bn);
                tv.z = f2bf(acc[i][j][2] + bn);
                tv.w = f2bf(acc[i][j][3] + bn);
                *(ushort4*)&Tl[w][col][quad * 4] = tv;
                #pragma unroll
                for (int rr = 0; rr < 4; ++rr) {
                    const int c = n0 - 2*CC + cn + j*16 + quad*4 + rr;
                    const int h = c / DD, d = c % DD;
                    const int m = m0 + rm + i*16 + col;
                    const int b = m >> 11, t = m & 2047;
                    Vt[((size_t)(b*HH + h)*DD + d)*TT + t] = Tl[w][quad*4 + rr][col];
                }
            }
        }
    }
}

// ---------------------------------------------------------------------------
// Kernel: flash attention, split-K partials.  R12: chunk size 8 -> 6.
// 640 blocks @2.5/CU left tail CUs with 3x8=24 tiles vs mean 17 (makespan-
// limited). Now 51 items/bh (chunks of <=6 tiles), 816 blocks ~3.19/CU:
// per-CU max ~18-20 tiles. Heavy-first: all 6-tile items dispatch first,
// the 48 lightest (2-4 tile) blocks are the only post-768 stragglers.
// Inner loop identical to R8/R11 (proven); only mapping/tables change.
//   item encode: code = qb*8+ci;  kts = ci*6;  kte = min(kts+6, 2qb+2)
//   NC[qb] = ceil((2qb+2)/6),  BSE = prefix(NC),  total 51
// ---------------------------------------------------------------------------
__device__ const unsigned char RANK2ITEM[51] = {
    // 6-tile items (40), qb desc
    120,121,122,123,124, 112,113,114,115,116, 104,105,106,107,
    96,97,98,99, 88,89,90,91, 80,81,82, 72,73,74, 64,65,66,
    56,57, 48,49, 40,41, 32, 24, 16,
    // 4-tile items (5)
    108,83,58,33,8,
    // 2-tile items (6)
    125,100,75,50,25,0
};
__device__ const unsigned char NC_TAB[16]  = {1,1,1,2,2,2,3,3,3,4,4,4,5,5,5,6};
__device__ const unsigned char BSE_TAB[16] = {0,1,2,3,5,7,9,12,15,18,22,26,30,35,40,45};

__global__ __launch_bounds__(256, 3) void attn_mfma_kernel(
    const ushort* __restrict__ Qb, const ushort* __restrict__ Kb,
    const ushort* __restrict__ Vt, ushort* __restrict__ Opart,
    float* __restrict__ Mpart, float* __restrict__ Lpart)
{
    __shared__ __align__(16) ushort Kl[64][104];     // [key][d], +8 pad
    __shared__ __align__(16) ushort Vl[96][72];      // [d][key], +8 pad
    __shared__ __align__(16) ushort Pl[4][16][72];   // per-wave P round-trip

    const int rank = blockIdx.x >> 4;    // 0..50, heavy-first
    const int bh   = blockIdx.x & 15;    // low bits -> XCD = bh&7 (L2 locality)
    const int code = RANK2ITEM[rank];
    const int qb = code >> 3, ci = code & 7;
    const int it = bh * 51 + BSE_TAB[qb] + ci;   // canonical item id

    const int tid  = threadIdx.x;
    const int w    = tid >> 6;
    const int lane = tid & 63;
    const int quad = lane >> 4;
    const int col  = lane & 15;
    const int q0   = qb * 128;

    bf16x8 qf[2][3];
    #pragma unroll
    for (int ih = 0; ih < 2; ++ih) {
        const int qrow = q0 + ih*64 + w*16 + col;
        const ushort* Qp = Qb + ((size_t)bh*TT + qrow)*DD;
        #pragma unroll
        for (int ks = 0; ks < 3; ++ks)
            qf[ih][ks] = *(const bf16x8*)(Qp + ks*32 + quad*8);
    }

    const ushort* Kg = Kb + (size_t)bh*TT*DD;
    const ushort* Vg = Vt + (size_t)bh*DD*TT;

    bf16x8 ones;
    #pragma unroll
    for (int e = 0; e < 8; ++e)
        ones[e] = __builtin_bit_cast(__bf16, (ushort)0x3F80);

    f32x4 O[2][7] = {};                   // [half][c2]; O[ih][6] = l
    float mrow[2][4];
    #pragma unroll
    for (int ih = 0; ih < 2; ++ih)
        #pragma unroll
        for (int r = 0; r < 4; ++r) mrow[ih][r] = -1e30f;

    const int kts = ci * 6;
    const int kte = min(kts + 6, 2*qb + 2);

    for (int kt = kts; kt < kte; ++kt) {
        const int k0 = kt * 64;
        __syncthreads();
        #pragma unroll
        for (int i = 0; i < 3; ++i) {
            int l = tid + i*256;
            int row = l / 12, ch = l % 12;
            uint4 vv = *(const uint4*)(Kg + (size_t)(k0 + row)*DD + ch*8);
            *(uint4*)&Kl[row][ch*8] = vv;
        }
        #pragma unroll
        for (int i = 0; i < 3; ++i) {
            int l = tid + i*256;
            int row = l / 8, ch = l % 8;
            uint4 vv = *(const uint4*)(Vg + (size_t)row*TT + k0 + ch*8);
            *(uint4*)&Vl[row][ch*8] = vv;
        }
        __syncthreads();

        #pragma unroll
        for (int ih = 0; ih < 2; ++ih) {
            f32x4 s[4];
            #pragma unroll
            for (int c = 0; c < 4; ++c) {
                f32x4 a = {0.f, 0.f, 0.f, 0.f};
                #pragma unroll
                for (int ks = 0; ks < 3; ++ks) {
                    bf16x8 bf = *(const bf16x8*)&Kl[c*16 + col][ks*32 + quad*8];
                    a = __builtin_amdgcn_mfma_f32_16x16x32_bf16(qf[ih][ks], bf, a, 0, 0, 0);
                }
                s[c] = a;
            }

            if (kt >= 2*qb + ih) {
                #pragma unroll
                for (int c = 0; c < 4; ++c)
                    #pragma unroll
                    for (int r = 0; r < 4; ++r) {
                        const int qabs = q0 + ih*64 + w*16 + quad*4 + r;
                        const int kabs = k0 + c*16 + col;
                        if (kabs > qabs) s[c][r] = -1e30f;
                    }
            }

            float mx4[4];
            #pragma unroll
            for (int r = 0; r < 4; ++r) {
                float mx = fmaxf(fmaxf(s[0][r], s[1][r]), fmaxf(s[2][r], s[3][r]));
                mx = fmaxf(mx, __shfl_xor(mx, 1, 64));
                mx = fmaxf(mx, __shfl_xor(mx, 2, 64));
                mx = fmaxf(mx, __shfl_xor(mx, 4, 64));
                mx = fmaxf(mx, __shfl_xor(mx, 8, 64));
                mx4[r] = mx;
            }
            const bool grow = (mx4[0] > mrow[ih][0] + 8.f) || (mx4[1] > mrow[ih][1] + 8.f) ||
                              (mx4[2] > mrow[ih][2] + 8.f) || (mx4[3] > mrow[ih][3] + 8.f);
            if (__any(grow)) {
                #pragma unroll
                for (int r = 0; r < 4; ++r) {
                    const float mnew  = fmaxf(mrow[ih][r], mx4[r]);
                    const float alpha = __expf(mrow[ih][r] - mnew);
                    mrow[ih][r] = mnew;
                    #pragma unroll
                    for (int c2 = 0; c2 < 7; ++c2)
                        O[ih][c2][r] *= alpha;
                }
            }

            float ps[4][4];
            #pragma unroll
            for (int r = 0; r < 4; ++r)
                #pragma unroll
                for (int c = 0; c < 4; ++c)
                    ps[c][r] = __expf(s[c][r] - mrow[ih][r]);

            #pragma unroll
            for (int c = 0; c < 4; ++c)
                #pragma unroll
                for (int r = 0; r < 4; ++r)
                    Pl[w][quad*4 + r][c*16 + col] = f2bf(ps[c][r]);

            bf16x8 pf0 = *(const bf16x8*)&Pl[w][col][quad*8];
            bf16x8 pf1 = *(const bf16x8*)&Pl[w][col][32 + quad*8];

            #pragma unroll
            for (int c2 = 0; c2 < 6; ++c2) {
                bf16x8 vb0 = *(const bf16x8*)&Vl[c2*16 + col][quad*8];
                bf16x8 vb1 = *(const bf16x8*)&Vl[c2*16 + col][32 + quad*8];
                O[ih][c2] = __builtin_amdgcn_mfma_f32_16x16x32_bf16(pf0, vb0, O[ih][c2], 0, 0, 0);
                O[ih][c2] = __builtin_amdgcn_mfma_f32_16x16x32_bf16(pf1, vb1, O[ih][c2], 0, 0, 0);
            }
            O[ih][6] = __builtin_amdgcn_mfma_f32_16x16x32_bf16(pf0, ones, O[ih][6], 0, 0, 0);
            O[ih][6] = __builtin_amdgcn_mfma_f32_16x16x32_bf16(pf1, ones, O[ih][6], 0, 0, 0);
        }
    }

    const size_t slot = (size_t)it;
    #pragma unroll
    for (int ih = 0; ih < 2; ++ih) {
        #pragma unroll
        for (int r = 0; r < 4; ++r) {
            const int rl = ih*64 + w*16 + quad*4 + r;
            ushort* Op = Opart + (slot*128 + rl)*DD;
            #pragma unroll
            for (int c2 = 0; c2 < 6; ++c2)
                Op[c2*16 + col] = f2bf(O[ih][c2][r]);
        }
        if (col == 0) {
            #pragma unroll
            for (int r = 0; r < 4; ++r) {
                const int rl = ih*64 + w*16 + quad*4 + r;
                Mpart[slot*128 + rl] = mrow[ih][r];
                Lpart[slot*128 + rl] = O[ih][6][r];
            }
        }
    }
}

// ---------------------------------------------------------------------------
// Kernel: combine split-K partials -> Yb (bf16).  R12: NC/BSE tables.
// Grid (32, 16): x covers 64 q-rows; qb = x>>1, half = x&1.
// ---------------------------------------------------------------------------
__global__ __launch_bounds__(256) void attn_combine_kernel(
    const ushort* __restrict__ Opart, const float* __restrict__ Mpart,
    const float* __restrict__ Lpart, ushort* __restrict__ Yb)
{
    const int x    = blockIdx.x;
    const int bh   = blockIdx.y;
    const int qb   = x >> 1;
    const int half = x & 1;
    const int nC   = NC_TAB[qb];
    const int item0 = bh * 51 + BSE_TAB[qb];

    const int tid = threadIdx.x;
    const int row = tid >> 2;
    const int jj  = tid & 3;
    const int rowin = half*64 + row;

    float m[6], f[6];
    float M = -1e30f;
    for (int c = 0; c < nC; ++c) {
        m[c] = Mpart[(size_t)(item0 + c)*128 + rowin];
        M = fmaxf(M, m[c]);
    }
    float L = 0.f;
    for (int c = 0; c < nC; ++c) {
        f[c] = __expf(m[c] - M);
        L += Lpart[(size_t)(item0 + c)*128 + rowin] * f[c];
    }
    const float invL = 1.0f / L;

    float acc[24] = {};
    for (int c = 0; c < nC; ++c) {
        const ushort* Op = Opart + ((size_t)(item0 + c)*128 + rowin)*DD + jj*24;
        const float fc = f[c];
        #pragma unroll
        for (int v = 0; v < 3; ++v) {
            uint4 pk = *(const uint4*)(Op + v*8);
            const ushort* us = (const ushort*)&pk;
            #pragma unroll
            for (int e = 0; e < 8; ++e)
                acc[v*8 + e] += fc * bf2f(us[e]);
        }
    }

    const int q = x*64 + row;
    const int b = bh >> 3, h = bh & 7;
    ushort outv[24];
    #pragma unroll
    for (int e = 0; e < 24; ++e) outv[e] = f2bf(acc[e] * invL);
    ushort* Yp = Yb + ((size_t)b*TT + q)*CC + h*DD + jj*24;
    #pragma unroll
    for (int v = 0; v < 3; ++v)
        *(uint4*)(Yp + v*8) = *(const uint4*)&outv[v*8];
}

// ---------------------------------------------------------------------------
// Kernel: proj GEMM (bf16 MFMA), out = Yb @ W_proj + b_proj, fp32 out.
// Grid 384 (1D), XCD panel mapping (unchanged from R8).
// ---------------------------------------------------------------------------
__global__ __launch_bounds__(256) void proj_mfma_kernel(
    const ushort* __restrict__ Yb, const ushort* __restrict__ Wpt,
    const float* __restrict__ bias, float* __restrict__ out)
{
    __shared__ __align__(16) ushort Al[3 * 64 * 32];
    __shared__ __align__(16) ushort Bl[3 * 128 * 32];

    const int bid = blockIdx.x;
    const int xcd = bid & 7;
    const int idx = bid >> 3;            // 0..47
    const int wk  = xcd * 48 + idx;
    const int ni  = wk % 6;
    const int mi  = wk / 6;              // xcd owns mi in [xcd*8, xcd*8+8)
    const int m0 = mi * 64;
    const int n0 = ni * 128;

    f32x4 acc[2][4] = {};
    mfma_gemm64_768(Yb, Wpt, m0, n0, Al, Bl, acc);

    const int tid  = threadIdx.x;
    const int w    = tid >> 6;
    const int lane = tid & 63;
    const int quad = lane >> 4;
    const int col  = lane & 15;
    const int rm   = (w >> 1) * 32;
    const int cn   = (w & 1) * 64;

    #pragma unroll
    for (int i = 0; i < 2; ++i) {
        #pragma unroll
        for (int j = 0; j < 4; ++j) {
            const int n = n0 + cn + j*16 + col;
            const float bn = bias[n];
            #pragma unroll
            for (int r = 0; r < 4; ++r) {
                const int m = m0 + rm + i*16 + quad*4 + r;
                out[(size_t)m*CC + n] = acc[i][j][r] + bn;
            }
        }
    }
}

extern "C" void kernel_launch(void* const* d_in, const int* in_sizes, int n_in,
                              void* d_out, int out_size, void* d_ws, size_t ws_size,
                              hipStream_t stream) {
    const float* x      = (const float*)d_in[0];
    const float* W_attn = (const float*)d_in[1];
    const float* b_attn = (const float*)d_in[2];
    const float* W_proj = (const float*)d_in[3];
    const float* b_proj = (const float*)d_in[4];
    float* out = (float*)d_out;

    const size_t SLICE   = (size_t)BH * TT * DD;   // 3,145,728
    const size_t OPART_E = (size_t)816 * 128 * DD; // 10,027,008 bf16
    ushort* Opart = (ushort*)d_ws;                 // [816][128][96] bf16
    ushort* xb    = Opart;                         // aliases Opart (xb dead before attn)
    ushort* Qb    = Opart + OPART_E;
    ushort* Kb    = Qb  + SLICE;
    ushort* Vt    = Kb  + SLICE;
    ushort* Yb    = Vt  + SLICE;
    ushort* Wat   = Yb  + SLICE;                   // [2304][768]
    ushort* Wpt   = Wat + (size_t)N3 * CC;         // [768][768]
    float*  Mpart = (float*)(Wpt + (size_t)CC * CC);  // [816][128]
    float*  Lpart = Mpart + (size_t)816 * 128;

    prep_kernel<<<dim3(2112), 256, 0, stream>>>(x, xb, W_attn, Wat, W_proj, Wpt);
    qkv_mfma_kernel<<<dim3(1152), 256, 0, stream>>>(
        xb, Wat, b_attn, Qb, Kb, Vt);
    attn_mfma_kernel<<<dim3(816), 256, 0, stream>>>(
        Qb, Kb, Vt, Opart, Mpart, Lpart);
    attn_combine_kernel<<<dim3(32, BH), 256, 0, stream>>>(
        Opart, Mpart, Lpart, Yb);
    proj_mfma_kernel<<<dim3(384), 256, 0, stream>>>(
        Yb, Wpt, b_proj, out);
}